// Round 10
// baseline (56.841 us; speedup 1.0000x reference)
//
#include <hip/hip_runtime.h>

#define CROP_S 14
#define NPIX   196                  // 14*14
#define NCH    256
#define CPB    16                   // channels per block
#define NGRP   (NCH / CPB)          // 16 blocks per proposal
#define PROWS  12                   // patch rows (span provably <= 12)
#define PCOLS  16                   // patch cols (span<=11 + <=3 align slack, float4-aligned)
#define PSZ    (PROWS * PCOLS)      // 192 floats per channel
#define STAGE_V4 (CPB * PSZ / 4)    // 768 float4 loads -> 3 per thread
#define OUTV4  (CPB * NPIX / 4)     // 784 float4 per item
#define QPC    (NPIX / 4)           // 49 float4 per channel (exact!)

typedef float v4f __attribute__((ext_vector_type(4)));

__global__ __launch_bounds__(256) void roi_crop_kernel(
    const float* __restrict__ f0, const float* __restrict__ f1,
    const float* __restrict__ f2, const float* __restrict__ f3,
    const float* __restrict__ proposals, float* __restrict__ out)
{
    __shared__ float s_patch[CPB * PSZ];      // 12 KB: [c][12][16]
    __shared__ int   s_o00[NPIX];             // per-pixel corner base
    __shared__ float s_wx[NPIX], s_wy[NPIX];  // per-pixel fracs (2.4 KB total)

    const int bid = blockIdx.x;
    const int n   = bid >> 4;          // proposal
    const int cg  = bid & (NGRP - 1);  // channel group
    const int c0  = cg * CPB;
    const int tid = threadIdx.x;

    // ---- per-proposal box / level (uniform across block; L2-hit loads) ----
    const float px0 = proposals[n * 7 + 1];
    const float py0 = proposals[n * 7 + 2];
    const float px1 = proposals[n * 7 + 3];
    const float py1 = proposals[n * 7 + 4];

    const float size = sqrtf((px1 - px0) * (py1 - py0));
    int lvl = 0;
    float bd = fabsf(size - 8.0f);
    {
        float d1 = fabsf(size - 16.0f);
        if (d1 < bd) { bd = d1; lvl = 1; }
        float d2 = fabsf(size - 32.0f);
        if (d2 < bd) { bd = d2; lvl = 2; }
        float d3 = fabsf(size - 64.0f);
        if (d3 < bd) { bd = d3; lvl = 3; }
    }

    const float* f = (lvl == 0) ? f0 : (lvl == 1) ? f1 : (lvl == 2) ? f2 : f3;
    const float stride = (float)(2 << lvl);   // 2,4,8,16 (pow2 -> exact divide)
    const int   M      = 256 >> lvl;          // H == W
    const int   HW     = M * M;

    const float x0s = px0 / stride, y0s = py0 / stride;
    const float x1s = px1 / stride, y1s = py1 / stride;
    const float bw = (x1s - x0s) / (float)CROP_S;
    const float bh = (y1s - y0s) / (float)CROP_S;

    // patch origin: floor of minimal sample coord; x aligned down to float4
    const int ylo  = min(max((int)floorf(y0s + 0.5f * bh - 0.5f), 0), M - 1);
    int xlo4 = min(max((int)floorf(x0s + 0.5f * bw - 0.5f), 0), M - 1) & ~3;
    xlo4 = min(xlo4, M - PCOLS);              // vector loads stay inside tensor

    // ---- stage CPB channels x 12x16 patch via float4 (3 per thread) ----
    {
        const float* fbase = f + (size_t)c0 * HW + xlo4;
        #pragma unroll
        for (int it = 0; it < STAGE_V4 / 256; ++it) {
            const int sidx = it * 256 + tid;         // [0,768)
            const int c    = sidx / (PSZ / 4);       // /48
            const int rem  = sidx - c * (PSZ / 4);
            const int r    = rem >> 2;               // row 0..11
            const int q    = rem & 3;                // col quad
            const int gy   = min(ylo + r, M - 1);    // edge-replicate rows
            const v4f v = *reinterpret_cast<const v4f*>(
                fbase + (size_t)c * HW + gy * M + q * 4);
            *reinterpret_cast<v4f*>(&s_patch[sidx * 4]) = v;
        }
    }

    // ---- per-pixel bilinear params into LDS (same phase as staging) ----
    if (tid < NPIX) {
        const int y = tid / CROP_S;
        const int x = tid - y * CROP_S;
        const float xs = x0s + ((float)x + 0.5f) * bw - 0.5f;
        const float ys = y0s + ((float)y + 0.5f) * bh - 0.5f;
        const float fx = floorf(xs), fy = floorf(ys);
        // frac BEFORE clip (matches reference)
        s_wx[tid] = xs - fx;
        s_wy[tid] = ys - fy;
        // Upper clamp provably never binds: xi1 == xi0+1, yi1 == yi0+1 always.
        const int xi0 = min(max((int)fx, 0), M - 1);
        const int yi0 = min(max((int)fy, 0), M - 1);
        const int ci0 = min(xi0 - xlo4, PCOLS - 2);
        const int ri0 = min(yi0 - ylo,  PROWS - 2);
        s_o00[tid] = ri0 * PCOLS + ci0;       // corners at +0, +1, +16, +17
    }
    __syncthreads();   // the ONLY barrier

    // ---- fused interp + full-line float4 NT writeout (all 256 lanes) ----
    v4f* ob = reinterpret_cast<v4f*>(
        out + (size_t)n * (NCH * NPIX) + (size_t)c0 * NPIX);  // 16B-aligned
    #pragma unroll
    for (int i = 0; i < 4; ++i) {
        const int idx4 = i * 256 + tid;       // [0,1024) vs OUTV4=784
        if (idx4 < OUTV4) {
            const int c  = idx4 / QPC;        // channel (float4 never crosses channels)
            const int pq = idx4 - c * QPC;
            const int p0 = pq * 4;            // 4 consecutive pixels
            const float* pp = s_patch + c * PSZ;
            v4f v;
            #pragma unroll
            for (int j = 0; j < 4; ++j) {
                const int   p  = p0 + j;
                const int   o  = s_o00[p];
                const float wx = s_wx[p];
                const float wy = s_wy[p];
                const float v00 = pp[o],     v01 = pp[o + 1];
                const float v10 = pp[o + PCOLS], v11 = pp[o + PCOLS + 1];
                const float r0 = v00 + wx * (v01 - v00);
                const float r1 = v10 + wx * (v11 - v10);
                v[j] = r0 + wy * (r1 - r0);
            }
            __builtin_nontemporal_store(v, ob + idx4);
        }
    }
}

extern "C" void kernel_launch(void* const* d_in, const int* in_sizes, int n_in,
                              void* d_out, int out_size, void* d_ws, size_t ws_size,
                              hipStream_t stream) {
    const float* f0 = (const float*)d_in[0];
    const float* f1 = (const float*)d_in[1];
    const float* f2 = (const float*)d_in[2];
    const float* f3 = (const float*)d_in[3];
    const float* proposals = (const float*)d_in[4];
    float* out = (float*)d_out;

    const int N = in_sizes[4] / 7;   // 1024 proposals

    roi_crop_kernel<<<dim3(N * NGRP), dim3(256), 0, stream>>>(f0, f1, f2, f3, proposals, out);
}